// Round 4
// baseline (19106.720 us; speedup 1.0000x reference)
//
#include <hip/hip_runtime.h>

// Problem dims
#define DP   256
#define DD   320
#define KK   10
#define CC   10
#define DOUT 64
#define SEQn 512
#define BB   32
#define SI   100
#define NPEER 8
#define RPP  400     // weight rows per peer (3200/8)
#define NTH  640     // 10 waves

// ws layout (4-byte words)
#define CTRW      (BB*32)
#define PS        448            // pub entry stride (floats)
#define UP_SL     0
#define ZA_SL     320
#define ZO_SL     384
#define PUBHALF   (BB*NPEER*PS)
#define PUB_OFF   CTRW

__global__ void prep_kernel(int* ctr) {
    int i = blockIdx.x * blockDim.x + threadIdx.x;
    if (i < CTRW) ctr[i] = 0;
}

// 8-peer barrier: monotonic counter, device-scope atomics.
__device__ __forceinline__ void gbar(int* c, int target) {
    __syncthreads();
    if (threadIdx.x == 0) {
        __threadfence();
        atomicAdd(c, 1);
        while (__hip_atomic_load(c, __ATOMIC_ACQUIRE, __HIP_MEMORY_SCOPE_AGENT) < target)
            __builtin_amdgcn_s_sleep(1);
        __threadfence();
    }
    __syncthreads();
}

__global__ __launch_bounds__(NTH) void recur_kernel(
    const int* __restrict__ sentence, const int* __restrict__ speaker,
    const float* __restrict__ LutP, const float* __restrict__ LutS,
    const float* __restrict__ NaW,  const float* __restrict__ NaB,
    const float* __restrict__ NuW,  const float* __restrict__ NuB,
    const float* __restrict__ NoW,  const float* __restrict__ NoB,
    const float* __restrict__ FuW,  const float* __restrict__ FuB,
    const float* __restrict__ FoW,  const float* __restrict__ FoB,
    float* __restrict__ ws, const int* __restrict__ Tptr,
    float* __restrict__ out)
{
    const int blk = blockIdx.x;
    const int b = blk >> 3;      // batch
    const int s = blk & 7;       // peer slice (== XCD under round-robin)
    const int tid = threadIdx.x;
    int* ctr = (int*)ws + b * 32;
    float* pub = ws + PUB_OFF;

    extern __shared__ float dynpad[];   // occupancy limiter (unused)

    __shared__ float xS[3200];     // full state copy, xS[d*10+k]
    __shared__ float part[2560];
    __shared__ float alpha[SEQn];
    __shared__ float fos[RPP];
    __shared__ float hpart[640];
    __shared__ float col[DD];
    __shared__ float idt[DP];
    __shared__ float identsh[DP];
    __shared__ float nub[DD];
    __shared__ float ucol[DD];
    __shared__ float upl[DD];
    __shared__ float hist[128];
    __shared__ float aout[32];
    __shared__ float nab[32];
    __shared__ float naU[32];
    __shared__ float noU[DOUT];
    __shared__ float foNo[DOUT];
    __shared__ float o_prev[DOUT];
    __shared__ float mu[CC], sgg[CC], gg[CC];
    __shared__ int   sent[SEQn];

    const int rbase0 = s * RPP;
    const int dbase0 = rbase0 / KK;   // 40 feature dims per slice

    // ---------------- prologue ----------------
    if (Tptr[0] == -12345) dynpad[tid] = 0.f;   // keep dynpad live (never true)
    for (int i = tid; i < SEQn; i += NTH) sent[i] = sentence[b * SEQn + i];
    {
        const int spk = speaker[b];
        for (int d = tid; d < DP; d += NTH) identsh[d] = LutS[spk * DP + d];
    }
    for (int o = tid; o < DD; o += NTH) nub[o] = NuB[o];
    if (tid < 32) nab[tid] = (tid < 30) ? NaB[tid] : 0.f;
    if (tid < CC) mu[tid] = 0.f;
    __syncthreads();
    // idt = tanh(ident @ Fu_w + Fu_b)  (redundant per peer)
    if (tid < DP) {
        float acc = FuB[tid];
        for (int j = 0; j < DP; ++j) acc += identsh[j] * FuW[j * DP + tid];
        idt[tid] = tanhf(acc);
    }
    // fo rows for this slice
    if (tid < RPP) {
        int r = rbase0 + tid;
        float acc = FoB[r];
        for (int j = 0; j < DP; ++j) acc += identsh[j] * FoW[j * 3200 + r];
        fos[tid] = acc;
    }
    // naU[c] = sum_d NuB[d]*NaW[10d][c]   (tap0 bias fold, step-invariant)
    if (tid >= 512 && tid < 544) {
        int c = tid - 512;
        float v = 0.f;
        if (c < 30) for (int d = 0; d < DD; ++d) v += nub[d] * NaW[(10 * d) * 30 + c];
        naU[c] = v;
    }
    // noU[j] = sum_d NuB[d]*NoW[10d][j]
    if (tid >= 544 && tid < 608) {
        int j = tid - 544;
        float v = 0.f;
        for (int d = 0; d < DD; ++d) v += nub[d] * NoW[(10 * d) * 64 + j];
        noU[j] = v;
    }
    __syncthreads();
    // partial foNo over this slice's rows
    {
        int o = tid & 63, rg = tid >> 6;  // 10 groups x 40 rows
        float acc = 0.f;
        for (int i = 0; i < 40; ++i) {
            int lr = rg * 40 + i;
            acc += fos[lr] * NoW[(rbase0 + lr) * 64 + o];
        }
        part[rg * 64 + o] = acc;
    }
    __syncthreads();
    if (tid < DOUT) {
        float v = 0.f;
        for (int rg = 0; rg < 10; ++rg) v += part[rg * 64 + tid];
        pub[(b * NPEER + s) * PS + ZO_SL + tid] = v;   // pub[0] zo-slot: foNo parts
    }
    // S0: every tap = [ident ; 0]
    for (int i = tid; i < 3200; i += NTH) {
        int d = i / KK;
        xS[i] = (d < DP) ? identsh[d] : 0.f;
    }
    __syncthreads();
    // za on S0 (ALL rows, tap0 = ident known)
    {
        int o = tid & 31, rg = tid >> 5;   // 20 groups x 20 rows
        float acc = 0.f;
        if (o < 30) {
            int rb = rbase0 + rg * 20;
            for (int i = 0; i < 20; ++i) acc += xS[rb + i] * NaW[(rb + i) * 30 + o];
        }
        part[rg * 32 + o] = acc;
    }
    __syncthreads();
    if (tid < 32) {
        float v = 0.f;
        if (tid < 30)
            for (int rg = 0; rg < 20; ++rg) v += part[rg * 32 + tid];
        pub[(b * NPEER + s) * PS + ZA_SL + tid] = v;
    }
    gbar(ctr, 8 * 1);
    if (tid < DOUT) {
        float v = NoB[tid];
        for (int p = 0; p < NPEER; ++p) v += pub[(b * NPEER + p) * PS + ZO_SL + tid];
        foNo[tid] = v;
    }
    __syncthreads();

    const int T = Tptr[0];
    const float4* nu4 = (const float4*)NuW;

    for (int i = 0; i < T; ++i) {
        const float* rbuf = pub + (i & 1) * PUBHALF + (size_t)b * NPEER * PS;
        float* wown = pub + ((i + 1) & 1) * PUBHALF + ((size_t)b * NPEER + s) * PS;

        // ---- assembly (reads rbuf published last step; identical on all peers) ----
        if (i == 0) {
            if (tid >= 320 && tid < 352) {
                int c = tid - 320;
                float v = nab[c];
                for (int p = 0; p < NPEER; ++p) v += rbuf[p * PS + ZA_SL + c];
                aout[c] = v;
            } else if (tid >= 384 && tid < 448) {
                o_prev[tid - 384] = 0.f;
            }
        } else {
            if (tid < DD) {
                float v = nub[tid];
                for (int p = 0; p < NPEER; ++p) v += rbuf[p * PS + UP_SL + tid];
                ucol[tid] = v;                       // assembled u_{i-1}
            } else if (tid < DD + 32) {
                int c = tid - DD;
                float v = nab[c] + naU[c];
                for (int p = 0; p < NPEER; ++p) v += rbuf[p * PS + ZA_SL + c];
                aout[c] = v;
            } else if (tid >= 384 && tid < 448) {
                int j = tid - 384;
                float v = foNo[j] + noU[j];
                for (int p = 0; p < NPEER; ++p) v += rbuf[p * PS + ZO_SL + j];
                o_prev[j] = v;
            }
        }
        __syncthreads();
        if (i > 0 && s == 0 && tid < DOUT)
            out[((size_t)(i - 1) * BB + b) * DOUT + tid] = o_prev[tid];
        // ---- B: attention state (redundant, identical across peers) ----
        if (tid < CC) {
            mu[tid] += 0.05f * expf(aout[tid]);
            sgg[tid] = expf(aout[10 + tid]);
            float m = -1e30f;
            for (int j = 0; j < CC; ++j) m = fmaxf(m, aout[20 + j]);
            float ssum = 0.f;
            for (int j = 0; j < CC; ++j) ssum += expf(aout[20 + j] - m);
            gg[tid] = expf(aout[20 + tid] - m) / ssum;
        }
        __syncthreads();
        // ---- C1: alpha ----
        if (tid < SEQn) {
            float J = (float)(tid + 1);
            float a = 0.f;
            #pragma unroll
            for (int c = 0; c < CC; ++c) { float dm = mu[c] - J; a += gg[c] * __expf(-0.5f * sgg[c] * dm * dm); }
            alpha[tid] = a * 0.3989422917366028f;
        }
        __syncthreads();
        // ---- hist: vocabulary-factored attention ----
        {
            int v = tid & 127, c = tid >> 7;    // 5 chunks x 128
            float h = 0.f;
            if (v < SI) {
                int i0 = c * 103, i1 = i0 + 103; if (i1 > SEQn) i1 = SEQn;
                for (int q = i0; q < i1; ++q) h += (sent[q] == v) ? alpha[q] : 0.f;
            }
            hpart[c * 128 + v] = h;
        }
        __syncthreads();
        if (tid < SI) {
            float h = 0.f;
            #pragma unroll
            for (int c = 0; c < 5; ++c) h += hpart[c * 128 + tid];
            hist[tid] = h;
        }
        __syncthreads();
        // ---- C2: col = [hist@LutP + idt ; o_prev/30] ----
        if (tid < DP) {
            float acc = 0.f;
            for (int v = 0; v < SI; v += 10) {
                float w[10];
                #pragma unroll
                for (int j = 0; j < 10; ++j) w[j] = LutP[(v + j) * DP + tid];
                #pragma unroll
                for (int j = 0; j < 10; ++j) acc += hist[v + j] * w[j];
            }
            col[tid] = acc + idt[tid];
        } else if (tid < DD) {
            col[tid] = o_prev[tid - DP] * (1.0f / 30.0f);
        }
        __syncthreads();
        // ---- D: fix tap0 := u_{i-1}, then shift-insert C_i ----
        if (tid < DD) {
            int base = tid * KK;
            float a0 = (i == 0) ? xS[base] : ucol[tid];
            float v[8];
            #pragma unroll
            for (int k = 0; k < 8; ++k) v[k] = xS[base + 1 + k];
            xS[base] = col[tid];
            xS[base + 1] = a0;
            #pragma unroll
            for (int k = 0; k < 8; ++k) xS[base + 2 + k] = v[k];
        }
        __syncthreads();
        // ---- E: u partials over slice rows (all taps; Sp local) ----
        {
            int oq = tid % 80, g = tid / 80;   // 8 groups x 50 rows
            int rb = rbase0 + g * 50;
            float4 acc = make_float4(0.f, 0.f, 0.f, 0.f);
            for (int q = 0; q < 50; q += 10) {
                float4 w[10]; float x[10];
                #pragma unroll
                for (int j = 0; j < 10; ++j) w[j] = nu4[(size_t)(rb + q + j) * 80 + oq];
                #pragma unroll
                for (int j = 0; j < 10; ++j) x[j] = xS[rb + q + j];
                #pragma unroll
                for (int j = 0; j < 10; ++j) {
                    acc.x += x[j] * w[j].x; acc.y += x[j] * w[j].y;
                    acc.z += x[j] * w[j].z; acc.w += x[j] * w[j].w;
                }
            }
            int o4 = oq * 4;
            part[g * 320 + o4]     = acc.x;
            part[g * 320 + o4 + 1] = acc.y;
            part[g * 320 + o4 + 2] = acc.z;
            part[g * 320 + o4 + 3] = acc.w;
        }
        __syncthreads();
        if (tid < DD) {
            float v = 0.f;
            #pragma unroll
            for (int g = 0; g < 8; ++g) v += part[g * 320 + tid];
            upl[tid] = v;
            wown[UP_SL + tid] = v;    // publish u partial
        }
        __syncthreads();
        // ---- za/zo partials for next step (k>=1 rows + own-u tap0 correction) ----
        {   // za main: 20 groups x (2 d-blocks x 9 rows)
            int o = tid & 31, rg = tid >> 5;
            float acc = 0.f;
            if (o < 30) {
                int d0 = dbase0 + rg * 2;
                #pragma unroll
                for (int dd = 0; dd < 2; ++dd) {
                    int base = (d0 + dd) * 10;
                    float wv[9], xv[9];
                    #pragma unroll
                    for (int k = 0; k < 9; ++k) wv[k] = NaW[(base + 1 + k) * 30 + o];
                    #pragma unroll
                    for (int k = 0; k < 9; ++k) xv[k] = xS[base + 1 + k];
                    #pragma unroll
                    for (int k = 0; k < 9; ++k) acc += xv[k] * wv[k];
                }
            }
            part[rg * 32 + o] = acc;
        }
        if (tid < 320) {   // za corr: 10 chunks x 32 d
            int c = tid & 31, dc = tid >> 5;
            float acc = 0.f;
            if (c < 30) {
                int d0 = dc * 32;
                for (int j = 0; j < 32; ++j) acc += upl[d0 + j] * NaW[(10 * (d0 + j)) * 30 + c];
            }
            part[640 + dc * 32 + c] = acc;
        }
        {   // zo main: 10 groups x (4 d-blocks x 9 rows)
            int o = tid & 63, rg = tid >> 6;
            float acc = 0.f;
            int d0 = dbase0 + rg * 4;
            #pragma unroll
            for (int dd = 0; dd < 4; ++dd) {
                int base = (d0 + dd) * 10;
                float wv[9], xv[9];
                #pragma unroll
                for (int k = 0; k < 9; ++k) wv[k] = NoW[(base + 1 + k) * 64 + o];
                #pragma unroll
                for (int k = 0; k < 9; ++k) xv[k] = xS[base + 1 + k];
                #pragma unroll
                for (int k = 0; k < 9; ++k) acc += xv[k] * wv[k];
            }
            part[960 + rg * 64 + o] = acc;
        }
        {   // zo corr: 10 chunks x 32 d
            int o = tid & 63, dc = tid >> 6;
            float acc = 0.f;
            int d0 = dc * 32;
            for (int j = 0; j < 32; ++j) acc += upl[d0 + j] * NoW[(10 * (d0 + j)) * 64 + o];
            part[1600 + dc * 64 + o] = acc;
        }
        __syncthreads();
        if (tid < 32) {
            float v = 0.f;
            #pragma unroll
            for (int rg = 0; rg < 20; ++rg) v += part[rg * 32 + tid];
            #pragma unroll
            for (int dc = 0; dc < 10; ++dc) v += part[640 + dc * 32 + tid];
            wown[ZA_SL + tid] = v;
        } else if (tid >= 64 && tid < 128) {
            int j = tid - 64;
            float v = 0.f;
            #pragma unroll
            for (int rg = 0; rg < 10; ++rg) v += part[960 + rg * 64 + j];
            #pragma unroll
            for (int dc = 0; dc < 10; ++dc) v += part[1600 + dc * 64 + j];
            wown[ZO_SL + j] = v;
        }
        gbar(ctr, 8 * (2 + i));
    }
    // final output o_{T-1}
    if (s == 0 && tid < DOUT) {
        const float* rbuf = pub + (T & 1) * PUBHALF + (size_t)b * NPEER * PS;
        float v = foNo[tid] + noU[tid];
        for (int p = 0; p < NPEER; ++p) v += rbuf[p * PS + ZO_SL + tid];
        out[((size_t)(T - 1) * BB + b) * DOUT + tid] = v;
    }
}

extern "C" void kernel_launch(void* const* d_in, const int* in_sizes, int n_in,
                              void* d_out, int out_size, void* d_ws, size_t ws_size,
                              hipStream_t stream) {
    const int*   sentence = (const int*)d_in[0];
    const int*   speaker  = (const int*)d_in[1];
    const float* LutP = (const float*)d_in[2];
    const float* LutS = (const float*)d_in[3];
    const float* NaW  = (const float*)d_in[4];
    const float* NaB  = (const float*)d_in[5];
    const float* NuW  = (const float*)d_in[6];
    const float* NuB  = (const float*)d_in[7];
    const float* NoW  = (const float*)d_in[8];
    const float* NoB  = (const float*)d_in[9];
    const float* FuW  = (const float*)d_in[10];
    const float* FuB  = (const float*)d_in[11];
    const float* FoW  = (const float*)d_in[12];
    const float* FoB  = (const float*)d_in[13];
    const int*   Tptr = (const int*)d_in[14];
    float* ws   = (float*)d_ws;
    float* outp = (float*)d_out;

    // force 1 block/CU: static (~39KB) + dynamic pad (48KB) > 160KB/2
    size_t dynbytes = 48 * 1024;
    if (hipFuncSetAttribute((const void*)recur_kernel,
                            hipFuncAttributeMaxDynamicSharedMemorySize,
                            (int)dynbytes) != hipSuccess)
        dynbytes = 0;   // graceful fallback: still correct, just packed

    hipLaunchKernelGGL(prep_kernel, dim3(1), dim3(1024), 0, stream, (int*)d_ws);
    hipLaunchKernelGGL(recur_kernel, dim3(BB * NPEER), dim3(NTH), dynbytes, stream,
                       sentence, speaker, LutP, LutS, NaW, NaB,
                       NuW, NuB, NoW, NoB, FuW, FuB, FoW, FoB,
                       ws, Tptr, outp);
}

// Round 5
// 18013.710 us; speedup vs baseline: 1.0607x; 1.0607x over previous
//
#include <hip/hip_runtime.h>

// Problem dims
#define DP   256
#define DD   320
#define KK   10
#define CC   10
#define DOUT 64
#define SEQn 512
#define BB   32
#define SI   100
#define NPEER 8
#define RPP  400     // weight rows per peer (3200/8)
#define NTH  640     // 10 waves

// ws layout (4-byte words)
#define CTRW      (BB*32)
#define PS        448            // pub entry stride (floats)
#define UP_SL     0
#define ZA_SL     320
#define ZO_SL     384
#define PUBHALF   (BB*NPEER*PS)
#define PUB_OFF   CTRW

__global__ void prep_kernel(int* ctr) {
    int i = blockIdx.x * blockDim.x + threadIdx.x;
    if (i < CTRW) ctr[i] = 0;
}

// LLC-direct (agent-scope, L1/L2-bypass) accessors for the exchange buffers.
__device__ __forceinline__ void stp(float* p, float v) {
    __hip_atomic_store(p, v, __ATOMIC_RELAXED, __HIP_MEMORY_SCOPE_AGENT);
}
__device__ __forceinline__ float ldp(const float* p) {
    return __hip_atomic_load(p, __ATOMIC_RELAXED, __HIP_MEMORY_SCOPE_AGENT);
}

// 8-peer barrier. RELEASE add (dirty writeback only, no invalidate);
// RELAXED poll (no per-iteration L2 invalidate). Data visibility comes from
// the stp/ldp LLC-direct accesses, so no acquire fence is needed.
__device__ __forceinline__ void gbar(int* c, int target) {
    __syncthreads();
    if (threadIdx.x == 0) {
        __hip_atomic_fetch_add(c, 1, __ATOMIC_RELEASE, __HIP_MEMORY_SCOPE_AGENT);
        while (__hip_atomic_load(c, __ATOMIC_RELAXED, __HIP_MEMORY_SCOPE_AGENT) < target)
            __builtin_amdgcn_s_sleep(2);
    }
    __syncthreads();
}

__global__ __launch_bounds__(NTH) void recur_kernel(
    const int* __restrict__ sentence, const int* __restrict__ speaker,
    const float* __restrict__ LutP, const float* __restrict__ LutS,
    const float* __restrict__ NaW,  const float* __restrict__ NaB,
    const float* __restrict__ NuW,  const float* __restrict__ NuB,
    const float* __restrict__ NoW,  const float* __restrict__ NoB,
    const float* __restrict__ FuW,  const float* __restrict__ FuB,
    const float* __restrict__ FoW,  const float* __restrict__ FoB,
    float* __restrict__ ws, const int* __restrict__ Tptr,
    float* __restrict__ out)
{
    const int blk = blockIdx.x;
    const int b = blk >> 3;      // batch
    const int s = blk & 7;       // peer slice (== XCD under round-robin)
    const int tid = threadIdx.x;
    int* ctr = (int*)ws + b * 32;
    float* pub = ws + PUB_OFF;

    __shared__ float xS[3200];     // full state copy, xS[d*10+k]
    __shared__ float part[2560];
    __shared__ float alpha[SEQn];
    __shared__ float fos[RPP];
    __shared__ float hpart[640];
    __shared__ float col[DD];
    __shared__ float idt[DP];
    __shared__ float identsh[DP];
    __shared__ float nub[DD];
    __shared__ float ucol[DD];
    __shared__ float upl[DD];
    __shared__ float hist[128];
    __shared__ float aout[32];
    __shared__ float nab[32];
    __shared__ float naU[32];
    __shared__ float noU[DOUT];
    __shared__ float foNo[DOUT];
    __shared__ float o_prev[DOUT];
    __shared__ float mu[CC], sgg[CC], gg[CC];
    __shared__ int   sent[SEQn];

    const int rbase0 = s * RPP;
    const int dbase0 = rbase0 / KK;   // 40 feature dims per slice

    // ---------------- prologue ----------------
    for (int i = tid; i < SEQn; i += NTH) sent[i] = sentence[b * SEQn + i];
    {
        const int spk = speaker[b];
        for (int d = tid; d < DP; d += NTH) identsh[d] = LutS[spk * DP + d];
    }
    for (int o = tid; o < DD; o += NTH) nub[o] = NuB[o];
    if (tid < 32) nab[tid] = (tid < 30) ? NaB[tid] : 0.f;
    if (tid < CC) mu[tid] = 0.f;
    __syncthreads();
    // idt = tanh(ident @ Fu_w + Fu_b)  (redundant per peer)
    if (tid < DP) {
        float acc = FuB[tid];
        for (int j = 0; j < DP; ++j) acc += identsh[j] * FuW[j * DP + tid];
        idt[tid] = tanhf(acc);
    }
    // fo rows for this slice
    if (tid < RPP) {
        int r = rbase0 + tid;
        float acc = FoB[r];
        for (int j = 0; j < DP; ++j) acc += identsh[j] * FoW[j * 3200 + r];
        fos[tid] = acc;
    }
    // naU[c] = sum_d NuB[d]*NaW[10d][c]   (tap0 bias fold, step-invariant)
    if (tid >= 512 && tid < 544) {
        int c = tid - 512;
        float v = 0.f;
        if (c < 30) for (int d = 0; d < DD; ++d) v += nub[d] * NaW[(10 * d) * 30 + c];
        naU[c] = v;
    }
    // noU[j] = sum_d NuB[d]*NoW[10d][j]
    if (tid >= 544 && tid < 608) {
        int j = tid - 544;
        float v = 0.f;
        for (int d = 0; d < DD; ++d) v += nub[d] * NoW[(10 * d) * 64 + j];
        noU[j] = v;
    }
    __syncthreads();
    // partial foNo over this slice's rows
    {
        int o = tid & 63, rg = tid >> 6;  // 10 groups x 40 rows
        float acc = 0.f;
        for (int i = 0; i < 40; ++i) {
            int lr = rg * 40 + i;
            acc += fos[lr] * NoW[(rbase0 + lr) * 64 + o];
        }
        part[rg * 64 + o] = acc;
    }
    __syncthreads();
    if (tid < DOUT) {
        float v = 0.f;
        for (int rg = 0; rg < 10; ++rg) v += part[rg * 64 + tid];
        stp(&pub[(b * NPEER + s) * PS + ZO_SL + tid], v);   // half0 zo-slot: foNo parts
    }
    // S0: every tap = [ident ; 0]
    for (int i = tid; i < 3200; i += NTH) {
        int d = i / KK;
        xS[i] = (d < DP) ? identsh[d] : 0.f;
    }
    __syncthreads();
    // za on S0 (ALL rows, tap0 = ident known)
    {
        int o = tid & 31, rg = tid >> 5;   // 20 groups x 20 rows
        float acc = 0.f;
        if (o < 30) {
            int rb = rbase0 + rg * 20;
            for (int i = 0; i < 20; ++i) acc += xS[rb + i] * NaW[(rb + i) * 30 + o];
        }
        part[rg * 32 + o] = acc;
    }
    __syncthreads();
    if (tid < 32) {
        float v = 0.f;
        if (tid < 30)
            for (int rg = 0; rg < 20; ++rg) v += part[rg * 32 + tid];
        stp(&pub[(b * NPEER + s) * PS + ZA_SL + tid], v);
    }
    gbar(ctr, 8 * 1);
    if (tid < DOUT) {
        float v = NoB[tid];
        for (int p = 0; p < NPEER; ++p) v += ldp(&pub[(b * NPEER + p) * PS + ZO_SL + tid]);
        foNo[tid] = v;
    }
    __syncthreads();

    const int T = Tptr[0];
    const float4* nu4 = (const float4*)NuW;

    for (int i = 0; i < T; ++i) {
        const float* rbuf = pub + (i & 1) * PUBHALF + (size_t)b * NPEER * PS;
        float* wown = pub + ((i + 1) & 1) * PUBHALF + ((size_t)b * NPEER + s) * PS;

        // ---- assembly (reads rbuf published last step; identical on all peers) ----
        if (i == 0) {
            if (tid >= 320 && tid < 352) {
                int c = tid - 320;
                float v = nab[c];
                for (int p = 0; p < NPEER; ++p) v += ldp(&rbuf[p * PS + ZA_SL + c]);
                aout[c] = v;
            } else if (tid >= 384 && tid < 448) {
                o_prev[tid - 384] = 0.f;
            }
        } else {
            if (tid < DD) {
                float v = nub[tid];
                for (int p = 0; p < NPEER; ++p) v += ldp(&rbuf[p * PS + UP_SL + tid]);
                ucol[tid] = v;                       // assembled u_{i-1}
            } else if (tid < DD + 32) {
                int c = tid - DD;
                float v = nab[c] + naU[c];
                for (int p = 0; p < NPEER; ++p) v += ldp(&rbuf[p * PS + ZA_SL + c]);
                aout[c] = v;
            } else if (tid >= 384 && tid < 448) {
                int j = tid - 384;
                float v = foNo[j] + noU[j];
                for (int p = 0; p < NPEER; ++p) v += ldp(&rbuf[p * PS + ZO_SL + j]);
                o_prev[j] = v;
            }
        }
        __syncthreads();
        if (i > 0 && s == 0 && tid < DOUT)
            out[((size_t)(i - 1) * BB + b) * DOUT + tid] = o_prev[tid];
        // ---- B: attention state (redundant, identical across peers) ----
        if (tid < CC) {
            mu[tid] += 0.05f * expf(aout[tid]);
            sgg[tid] = expf(aout[10 + tid]);
            float m = -1e30f;
            for (int j = 0; j < CC; ++j) m = fmaxf(m, aout[20 + j]);
            float ssum = 0.f;
            for (int j = 0; j < CC; ++j) ssum += expf(aout[20 + j] - m);
            gg[tid] = expf(aout[20 + tid] - m) / ssum;
        }
        __syncthreads();
        // ---- C1: alpha ----
        if (tid < SEQn) {
            float J = (float)(tid + 1);
            float a = 0.f;
            #pragma unroll
            for (int c = 0; c < CC; ++c) { float dm = mu[c] - J; a += gg[c] * __expf(-0.5f * sgg[c] * dm * dm); }
            alpha[tid] = a * 0.3989422917366028f;
        }
        __syncthreads();
        // ---- hist: vocabulary-factored attention ----
        {
            int v = tid & 127, c = tid >> 7;    // 5 chunks x 128
            float h = 0.f;
            if (v < SI) {
                int i0 = c * 103, i1 = i0 + 103; if (i1 > SEQn) i1 = SEQn;
                for (int q = i0; q < i1; ++q) h += (sent[q] == v) ? alpha[q] : 0.f;
            }
            hpart[c * 128 + v] = h;
        }
        __syncthreads();
        if (tid < SI) {
            float h = 0.f;
            #pragma unroll
            for (int c = 0; c < 5; ++c) h += hpart[c * 128 + tid];
            hist[tid] = h;
        }
        __syncthreads();
        // ---- C2: col = [hist@LutP + idt ; o_prev/30] ----
        if (tid < DP) {
            float acc = 0.f;
            for (int v = 0; v < SI; v += 10) {
                float w[10];
                #pragma unroll
                for (int j = 0; j < 10; ++j) w[j] = LutP[(v + j) * DP + tid];
                #pragma unroll
                for (int j = 0; j < 10; ++j) acc += hist[v + j] * w[j];
            }
            col[tid] = acc + idt[tid];
        } else if (tid < DD) {
            col[tid] = o_prev[tid - DP] * (1.0f / 30.0f);
        }
        __syncthreads();
        // ---- D: fix tap0 := u_{i-1}, then shift-insert C_i ----
        if (tid < DD) {
            int base = tid * KK;
            float a0 = (i == 0) ? xS[base] : ucol[tid];
            float v[8];
            #pragma unroll
            for (int k = 0; k < 8; ++k) v[k] = xS[base + 1 + k];
            xS[base] = col[tid];
            xS[base + 1] = a0;
            #pragma unroll
            for (int k = 0; k < 8; ++k) xS[base + 2 + k] = v[k];
        }
        __syncthreads();
        // ---- E: u partials over slice rows (all taps; Sp local) ----
        {
            int oq = tid % 80, g = tid / 80;   // 8 groups x 50 rows
            int rb = rbase0 + g * 50;
            float4 acc = make_float4(0.f, 0.f, 0.f, 0.f);
            for (int q = 0; q < 50; q += 10) {
                float4 w[10]; float x[10];
                #pragma unroll
                for (int j = 0; j < 10; ++j) w[j] = nu4[(size_t)(rb + q + j) * 80 + oq];
                #pragma unroll
                for (int j = 0; j < 10; ++j) x[j] = xS[rb + q + j];
                #pragma unroll
                for (int j = 0; j < 10; ++j) {
                    acc.x += x[j] * w[j].x; acc.y += x[j] * w[j].y;
                    acc.z += x[j] * w[j].z; acc.w += x[j] * w[j].w;
                }
            }
            int o4 = oq * 4;
            part[g * 320 + o4]     = acc.x;
            part[g * 320 + o4 + 1] = acc.y;
            part[g * 320 + o4 + 2] = acc.z;
            part[g * 320 + o4 + 3] = acc.w;
        }
        __syncthreads();
        if (tid < DD) {
            float v = 0.f;
            #pragma unroll
            for (int g = 0; g < 8; ++g) v += part[g * 320 + tid];
            upl[tid] = v;
            stp(&wown[UP_SL + tid], v);    // publish u partial
        }
        __syncthreads();
        // ---- za/zo partials for next step (k>=1 rows + own-u tap0 correction) ----
        {   // za main: 20 groups x (2 d-blocks x 9 rows)
            int o = tid & 31, rg = tid >> 5;
            float acc = 0.f;
            if (o < 30) {
                int d0 = dbase0 + rg * 2;
                #pragma unroll
                for (int dd = 0; dd < 2; ++dd) {
                    int base = (d0 + dd) * 10;
                    float wv[9], xv[9];
                    #pragma unroll
                    for (int k = 0; k < 9; ++k) wv[k] = NaW[(base + 1 + k) * 30 + o];
                    #pragma unroll
                    for (int k = 0; k < 9; ++k) xv[k] = xS[base + 1 + k];
                    #pragma unroll
                    for (int k = 0; k < 9; ++k) acc += xv[k] * wv[k];
                }
            }
            part[rg * 32 + o] = acc;
        }
        if (tid < 320) {   // za corr: 10 chunks x 32 d
            int c = tid & 31, dc = tid >> 5;
            float acc = 0.f;
            if (c < 30) {
                int d0 = dc * 32;
                for (int j = 0; j < 32; ++j) acc += upl[d0 + j] * NaW[(10 * (d0 + j)) * 30 + c];
            }
            part[640 + dc * 32 + c] = acc;
        }
        {   // zo main: 10 groups x (4 d-blocks x 9 rows)
            int o = tid & 63, rg = tid >> 6;
            float acc = 0.f;
            int d0 = dbase0 + rg * 4;
            #pragma unroll
            for (int dd = 0; dd < 4; ++dd) {
                int base = (d0 + dd) * 10;
                float wv[9], xv[9];
                #pragma unroll
                for (int k = 0; k < 9; ++k) wv[k] = NoW[(base + 1 + k) * 64 + o];
                #pragma unroll
                for (int k = 0; k < 9; ++k) xv[k] = xS[base + 1 + k];
                #pragma unroll
                for (int k = 0; k < 9; ++k) acc += xv[k] * wv[k];
            }
            part[960 + rg * 64 + o] = acc;
        }
        {   // zo corr: 10 chunks x 32 d
            int o = tid & 63, dc = tid >> 6;
            float acc = 0.f;
            int d0 = dc * 32;
            for (int j = 0; j < 32; ++j) acc += upl[d0 + j] * NoW[(10 * (d0 + j)) * 64 + o];
            part[1600 + dc * 64 + o] = acc;
        }
        __syncthreads();
        if (tid < 32) {
            float v = 0.f;
            #pragma unroll
            for (int rg = 0; rg < 20; ++rg) v += part[rg * 32 + tid];
            #pragma unroll
            for (int dc = 0; dc < 10; ++dc) v += part[640 + dc * 32 + tid];
            stp(&wown[ZA_SL + tid], v);
        } else if (tid >= 64 && tid < 128) {
            int j = tid - 64;
            float v = 0.f;
            #pragma unroll
            for (int rg = 0; rg < 10; ++rg) v += part[960 + rg * 64 + j];
            #pragma unroll
            for (int dc = 0; dc < 10; ++dc) v += part[1600 + dc * 64 + j];
            stp(&wown[ZO_SL + j], v);
        }
        gbar(ctr, 8 * (2 + i));
    }
    // final output o_{T-1}
    if (s == 0 && tid < DOUT) {
        const float* rbuf = pub + (T & 1) * PUBHALF + (size_t)b * NPEER * PS;
        float v = foNo[tid] + noU[tid];
        for (int p = 0; p < NPEER; ++p) v += ldp(&rbuf[p * PS + ZO_SL + tid]);
        out[((size_t)(T - 1) * BB + b) * DOUT + tid] = v;
    }
}

extern "C" void kernel_launch(void* const* d_in, const int* in_sizes, int n_in,
                              void* d_out, int out_size, void* d_ws, size_t ws_size,
                              hipStream_t stream) {
    const int*   sentence = (const int*)d_in[0];
    const int*   speaker  = (const int*)d_in[1];
    const float* LutP = (const float*)d_in[2];
    const float* LutS = (const float*)d_in[3];
    const float* NaW  = (const float*)d_in[4];
    const float* NaB  = (const float*)d_in[5];
    const float* NuW  = (const float*)d_in[6];
    const float* NuB  = (const float*)d_in[7];
    const float* NoW  = (const float*)d_in[8];
    const float* NoB  = (const float*)d_in[9];
    const float* FuW  = (const float*)d_in[10];
    const float* FuB  = (const float*)d_in[11];
    const float* FoW  = (const float*)d_in[12];
    const float* FoB  = (const float*)d_in[13];
    const int*   Tptr = (const int*)d_in[14];
    float* ws   = (float*)d_ws;
    float* outp = (float*)d_out;

    hipLaunchKernelGGL(prep_kernel, dim3(1), dim3(1024), 0, stream, (int*)d_ws);
    hipLaunchKernelGGL(recur_kernel, dim3(BB * NPEER), dim3(NTH), 0, stream,
                       sentence, speaker, LutP, LutS, NaW, NaB,
                       NuW, NuB, NoW, NoB, FuW, FuB, FoW, FoB,
                       ws, Tptr, outp);
}

// Round 7
// 17694.667 us; speedup vs baseline: 1.0798x; 1.0180x over previous
//
#include <hip/hip_runtime.h>

// Problem dims
#define DP   256
#define DD   320
#define KK   10
#define CC   10
#define DOUT 64
#define SEQn 512
#define BB   32
#define SI   100
#define NPEER 8
#define RPP  400     // weight rows per peer (3200/8)
#define NTH  640     // 10 waves

// ws layout (4-byte words)
#define CTRW      (BB*32)        // per-batch barrier counters
#define QCTR_OFF  CTRW           // 8 per-slice claim queues (+pad)
#define PUB_OFF   (CTRW + 32)
#define PS        448            // pub entry stride (floats)
#define UP_SL     0
#define ZA_SL     320
#define ZO_SL     384
#define PUBHALF   (BB*NPEER*PS)

__global__ void prep_kernel(int* ctr) {
    int idx = blockIdx.x * blockDim.x + threadIdx.x;
    int stride = gridDim.x * blockDim.x;
    for (int i = idx; i < CTRW + 32; i += stride) ctr[i] = 0;
}

// LLC-direct (agent-scope) accessors for the exchange buffers.
__device__ __forceinline__ void stp(float* p, float v) {
    __hip_atomic_store(p, v, __ATOMIC_RELAXED, __HIP_MEMORY_SCOPE_AGENT);
}
__device__ __forceinline__ float ldp(const float* p) {
    return __hip_atomic_load(p, __ATOMIC_RELAXED, __HIP_MEMORY_SCOPE_AGENT);
}

// 8-peer barrier: RELEASE add (writeback, no invalidate) + RELAXED poll.
__device__ __forceinline__ void gbar(int* c, int target) {
    __syncthreads();
    if (threadIdx.x == 0) {
        __hip_atomic_fetch_add(c, 1, __ATOMIC_RELEASE, __HIP_MEMORY_SCOPE_AGENT);
        while (__hip_atomic_load(c, __ATOMIC_RELAXED, __HIP_MEMORY_SCOPE_AGENT) < target)
            __builtin_amdgcn_s_sleep(2);
    }
    __syncthreads();
}

__global__ __launch_bounds__(NTH) void recur_kernel(
    const int* __restrict__ sentence, const int* __restrict__ speaker,
    const float* __restrict__ LutP, const float* __restrict__ LutS,
    const float* __restrict__ NaW,  const float* __restrict__ NaB,
    const float* __restrict__ NuW,  const float* __restrict__ NuB,
    const float* __restrict__ NoW,  const float* __restrict__ NoB,
    const float* __restrict__ FuW,  const float* __restrict__ FuB,
    const float* __restrict__ FoW,  const float* __restrict__ FoB,
    float* __restrict__ ws, const int* __restrict__ Tptr,
    float* __restrict__ out)
{
    const int tid = threadIdx.x;
    float* pub = ws + PUB_OFF;

    // ---- XCD-affine dynamic work claiming ----
    __shared__ int claim_item;
    if (tid == 0) {
        // HW_REG_XCC_ID = hwreg 20 on gfx950; imm = id | (size-1)<<11
        unsigned xcc = __builtin_amdgcn_s_getreg(20 | (31 << 11)) & 7u;
        int* qc = (int*)ws + QCTR_OFF;
        int item = -1;
        for (int k = 0; k < 8 && item < 0; ++k) {
            int q = (int)((xcc + (unsigned)k) & 7u);
            int pos = atomicAdd(&qc[q], 1);
            if (pos >= 0 && pos < BB) item = pos * NPEER + q;   // batch=pos, slice=q
        }
        if (item < 0) item = 0;   // unreachable when queues start at 0
        claim_item = item;
    }
    __syncthreads();
    const int b = claim_item >> 3;      // batch
    const int s = claim_item & 7;       // slice == local XCD (32 blocks/XCD)
    int* ctr = (int*)ws + b * 32;

    __shared__ float xS[3200];     // full state copy, xS[d*10+k]
    __shared__ float part[2560];
    __shared__ float alpha[SEQn];
    __shared__ float fos[RPP];
    __shared__ float hpart[640];
    __shared__ float col[DD];
    __shared__ float idt[DP];
    __shared__ float identsh[DP];
    __shared__ float nub[DD];
    __shared__ float ucol[DD];
    __shared__ float upl[DD];
    __shared__ float hist[128];
    __shared__ float aout[32];
    __shared__ float nab[32];
    __shared__ float naU[32];
    __shared__ float noU[DOUT];
    __shared__ float foNo[DOUT];
    __shared__ float o_prev[DOUT];
    __shared__ float mu[CC], sgg[CC], gg[CC];
    __shared__ int   sent[SEQn];

    const int rbase0 = s * RPP;
    const int dbase0 = rbase0 / KK;   // 40 feature dims per slice

    // ---------------- prologue ----------------
    for (int i = tid; i < SEQn; i += NTH) sent[i] = sentence[b * SEQn + i];
    {
        const int spk = speaker[b];
        for (int d = tid; d < DP; d += NTH) identsh[d] = LutS[spk * DP + d];
    }
    for (int o = tid; o < DD; o += NTH) nub[o] = NuB[o];
    if (tid < 32) nab[tid] = (tid < 30) ? NaB[tid] : 0.f;
    if (tid < CC) mu[tid] = 0.f;
    __syncthreads();
    // idt = tanh(ident @ Fu_w + Fu_b)  (redundant per peer)
    if (tid < DP) {
        float acc = FuB[tid];
        for (int j = 0; j < DP; ++j) acc += identsh[j] * FuW[j * DP + tid];
        idt[tid] = tanhf(acc);
    }
    // fo rows for this slice
    if (tid < RPP) {
        int r = rbase0 + tid;
        float acc = FoB[r];
        for (int j = 0; j < DP; ++j) acc += identsh[j] * FoW[j * 3200 + r];
        fos[tid] = acc;
    }
    // naU[c] = sum_d NuB[d]*NaW[10d][c]   (tap0 bias fold, step-invariant)
    if (tid >= 512 && tid < 544) {
        int c = tid - 512;
        float v = 0.f;
        if (c < 30) for (int d = 0; d < DD; ++d) v += nub[d] * NaW[(10 * d) * 30 + c];
        naU[c] = v;
    }
    // noU[j] = sum_d NuB[d]*NoW[10d][j]
    if (tid >= 544 && tid < 608) {
        int j = tid - 544;
        float v = 0.f;
        for (int d = 0; d < DD; ++d) v += nub[d] * NoW[(10 * d) * 64 + j];
        noU[j] = v;
    }
    __syncthreads();
    // partial foNo over this slice's rows
    {
        int o = tid & 63, rg = tid >> 6;  // 10 groups x 40 rows
        float acc = 0.f;
        for (int i = 0; i < 40; ++i) {
            int lr = rg * 40 + i;
            acc += fos[lr] * NoW[(rbase0 + lr) * 64 + o];
        }
        part[rg * 64 + o] = acc;
    }
    __syncthreads();
    if (tid < DOUT) {
        float v = 0.f;
        for (int rg = 0; rg < 10; ++rg) v += part[rg * 64 + tid];
        stp(&pub[(b * NPEER + s) * PS + ZO_SL + tid], v);   // half0 zo-slot: foNo parts
    }
    // S0: every tap = [ident ; 0]
    for (int i = tid; i < 3200; i += NTH) {
        int d = i / KK;
        xS[i] = (d < DP) ? identsh[d] : 0.f;
    }
    __syncthreads();
    // za on S0 (ALL rows, tap0 = ident known)
    {
        int o = tid & 31, rg = tid >> 5;   // 20 groups x 20 rows
        float acc = 0.f;
        if (o < 30) {
            int rb = rbase0 + rg * 20;
            for (int i = 0; i < 20; ++i) acc += xS[rb + i] * NaW[(rb + i) * 30 + o];
        }
        part[rg * 32 + o] = acc;
    }
    __syncthreads();
    if (tid < 32) {
        float v = 0.f;
        if (tid < 30)
            for (int rg = 0; rg < 20; ++rg) v += part[rg * 32 + tid];
        stp(&pub[(b * NPEER + s) * PS + ZA_SL + tid], v);
    }
    gbar(ctr, 8 * 1);
    if (tid < DOUT) {
        float v = NoB[tid];
        for (int p = 0; p < NPEER; ++p) v += ldp(&pub[(b * NPEER + p) * PS + ZO_SL + tid]);
        foNo[tid] = v;
    }
    __syncthreads();

    const int T = Tptr[0];
    const float4* nu4 = (const float4*)NuW;

    for (int i = 0; i < T; ++i) {
        const float* rbuf = pub + (i & 1) * PUBHALF + (size_t)b * NPEER * PS;
        float* wown = pub + ((i + 1) & 1) * PUBHALF + ((size_t)b * NPEER + s) * PS;

        // ---- assembly (reads rbuf published last step; identical on all peers) ----
        if (i == 0) {
            if (tid >= 320 && tid < 352) {
                int c = tid - 320;
                float v = nab[c];
                for (int p = 0; p < NPEER; ++p) v += ldp(&rbuf[p * PS + ZA_SL + c]);
                aout[c] = v;
            } else if (tid >= 384 && tid < 448) {
                o_prev[tid - 384] = 0.f;
            }
        } else {
            if (tid < DD) {
                float v = nub[tid];
                for (int p = 0; p < NPEER; ++p) v += ldp(&rbuf[p * PS + UP_SL + tid]);
                ucol[tid] = v;                       // assembled u_{i-1}
            } else if (tid < DD + 32) {
                int c = tid - DD;
                float v = nab[c] + naU[c];
                for (int p = 0; p < NPEER; ++p) v += ldp(&rbuf[p * PS + ZA_SL + c]);
                aout[c] = v;
            } else if (tid >= 384 && tid < 448) {
                int j = tid - 384;
                float v = foNo[j] + noU[j];
                for (int p = 0; p < NPEER; ++p) v += ldp(&rbuf[p * PS + ZO_SL + j]);
                o_prev[j] = v;
            }
        }
        __syncthreads();
        if (i > 0 && s == 0 && tid < DOUT)
            out[((size_t)(i - 1) * BB + b) * DOUT + tid] = o_prev[tid];
        // ---- B: attention state (redundant, identical across peers) ----
        if (tid < CC) {
            mu[tid] += 0.05f * expf(aout[tid]);
            sgg[tid] = expf(aout[10 + tid]);
            float m = -1e30f;
            for (int j = 0; j < CC; ++j) m = fmaxf(m, aout[20 + j]);
            float ssum = 0.f;
            for (int j = 0; j < CC; ++j) ssum += expf(aout[20 + j] - m);
            gg[tid] = expf(aout[20 + tid] - m) / ssum;
        }
        __syncthreads();
        // ---- C1: alpha ----
        if (tid < SEQn) {
            float J = (float)(tid + 1);
            float a = 0.f;
            #pragma unroll
            for (int c = 0; c < CC; ++c) { float dm = mu[c] - J; a += gg[c] * __expf(-0.5f * sgg[c] * dm * dm); }
            alpha[tid] = a * 0.3989422917366028f;
        }
        __syncthreads();
        // ---- hist: vocabulary-factored attention ----
        {
            int v = tid & 127, c = tid >> 7;    // 5 chunks x 128
            float h = 0.f;
            if (v < SI) {
                int i0 = c * 103, i1 = i0 + 103; if (i1 > SEQn) i1 = SEQn;
                for (int q = i0; q < i1; ++q) h += (sent[q] == v) ? alpha[q] : 0.f;
            }
            hpart[c * 128 + v] = h;
        }
        __syncthreads();
        if (tid < SI) {
            float h = 0.f;
            #pragma unroll
            for (int c = 0; c < 5; ++c) h += hpart[c * 128 + tid];
            hist[tid] = h;
        }
        __syncthreads();
        // ---- C2: col = [hist@LutP + idt ; o_prev/30] ----
        if (tid < DP) {
            float acc = 0.f;
            for (int v = 0; v < SI; v += 10) {
                float w[10];
                #pragma unroll
                for (int j = 0; j < 10; ++j) w[j] = LutP[(v + j) * DP + tid];
                #pragma unroll
                for (int j = 0; j < 10; ++j) acc += hist[v + j] * w[j];
            }
            col[tid] = acc + idt[tid];
        } else if (tid < DD) {
            col[tid] = o_prev[tid - DP] * (1.0f / 30.0f);
        }
        __syncthreads();
        // ---- D: fix tap0 := u_{i-1}, then shift-insert C_i ----
        if (tid < DD) {
            int base = tid * KK;
            float a0 = (i == 0) ? xS[base] : ucol[tid];
            float v[8];
            #pragma unroll
            for (int k = 0; k < 8; ++k) v[k] = xS[base + 1 + k];
            xS[base] = col[tid];
            xS[base + 1] = a0;
            #pragma unroll
            for (int k = 0; k < 8; ++k) xS[base + 2 + k] = v[k];
        }
        __syncthreads();
        // ---- E: u partials over slice rows (all taps; Sp local) ----
        {
            int oq = tid % 80, g = tid / 80;   // 8 groups x 50 rows
            int rb = rbase0 + g * 50;
            float4 acc = make_float4(0.f, 0.f, 0.f, 0.f);
            for (int q = 0; q < 50; q += 10) {
                float4 w[10]; float x[10];
                #pragma unroll
                for (int j = 0; j < 10; ++j) w[j] = nu4[(size_t)(rb + q + j) * 80 + oq];
                #pragma unroll
                for (int j = 0; j < 10; ++j) x[j] = xS[rb + q + j];
                #pragma unroll
                for (int j = 0; j < 10; ++j) {
                    acc.x += x[j] * w[j].x; acc.y += x[j] * w[j].y;
                    acc.z += x[j] * w[j].z; acc.w += x[j] * w[j].w;
                }
            }
            int o4 = oq * 4;
            part[g * 320 + o4]     = acc.x;
            part[g * 320 + o4 + 1] = acc.y;
            part[g * 320 + o4 + 2] = acc.z;
            part[g * 320 + o4 + 3] = acc.w;
        }
        __syncthreads();
        if (tid < DD) {
            float v = 0.f;
            #pragma unroll
            for (int g = 0; g < 8; ++g) v += part[g * 320 + tid];
            upl[tid] = v;
            stp(&wown[UP_SL + tid], v);    // publish u partial
        }
        __syncthreads();
        // ---- za/zo partials for next step (k>=1 rows + own-u tap0 correction) ----
        {   // za main: 20 groups x (2 d-blocks x 9 rows)
            int o = tid & 31, rg = tid >> 5;
            float acc = 0.f;
            if (o < 30) {
                int d0 = dbase0 + rg * 2;
                #pragma unroll
                for (int dd = 0; dd < 2; ++dd) {
                    int base = (d0 + dd) * 10;
                    float wv[9], xv[9];
                    #pragma unroll
                    for (int k = 0; k < 9; ++k) wv[k] = NaW[(base + 1 + k) * 30 + o];
                    #pragma unroll
                    for (int k = 0; k < 9; ++k) xv[k] = xS[base + 1 + k];
                    #pragma unroll
                    for (int k = 0; k < 9; ++k) acc += xv[k] * wv[k];
                }
            }
            part[rg * 32 + o] = acc;
        }
        if (tid < 320) {   // za corr: 10 chunks x 32 d
            int c = tid & 31, dc = tid >> 5;
            float acc = 0.f;
            if (c < 30) {
                int d0 = dc * 32;
                for (int j = 0; j < 32; ++j) acc += upl[d0 + j] * NaW[(10 * (d0 + j)) * 30 + c];
            }
            part[640 + dc * 32 + c] = acc;
        }
        {   // zo main: 10 groups x (4 d-blocks x 9 rows)
            int o = tid & 63, rg = tid >> 6;
            float acc = 0.f;
            int d0 = dbase0 + rg * 4;
            #pragma unroll
            for (int dd = 0; dd < 4; ++dd) {
                int base = (d0 + dd) * 10;
                float wv[9], xv[9];
                #pragma unroll
                for (int k = 0; k < 9; ++k) wv[k] = NoW[(base + 1 + k) * 64 + o];
                #pragma unroll
                for (int k = 0; k < 9; ++k) xv[k] = xS[base + 1 + k];
                #pragma unroll
                for (int k = 0; k < 9; ++k) acc += xv[k] * wv[k];
            }
            part[960 + rg * 64 + o] = acc;
        }
        {   // zo corr: 10 chunks x 32 d
            int o = tid & 63, dc = tid >> 6;
            float acc = 0.f;
            int d0 = dc * 32;
            for (int j = 0; j < 32; ++j) acc += upl[d0 + j] * NoW[(10 * (d0 + j)) * 64 + o];
            part[1600 + dc * 64 + o] = acc;
        }
        __syncthreads();
        if (tid < 32) {
            float v = 0.f;
            #pragma unroll
            for (int rg = 0; rg < 20; ++rg) v += part[rg * 32 + tid];
            #pragma unroll
            for (int dc = 0; dc < 10; ++dc) v += part[640 + dc * 32 + tid];
            stp(&wown[ZA_SL + tid], v);
        } else if (tid >= 64 && tid < 128) {
            int j = tid - 64;
            float v = 0.f;
            #pragma unroll
            for (int rg = 0; rg < 10; ++rg) v += part[960 + rg * 64 + j];
            #pragma unroll
            for (int dc = 0; dc < 10; ++dc) v += part[1600 + dc * 64 + j];
            stp(&wown[ZO_SL + j], v);
        }
        gbar(ctr, 8 * (2 + i));
    }
    // final output o_{T-1}
    if (s == 0 && tid < DOUT) {
        const float* rbuf = pub + (T & 1) * PUBHALF + (size_t)b * NPEER * PS;
        float v = foNo[tid] + noU[tid];
        for (int p = 0; p < NPEER; ++p) v += ldp(&rbuf[p * PS + ZO_SL + tid]);
        out[((size_t)(T - 1) * BB + b) * DOUT + tid] = v;
    }
}

extern "C" void kernel_launch(void* const* d_in, const int* in_sizes, int n_in,
                              void* d_out, int out_size, void* d_ws, size_t ws_size,
                              hipStream_t stream) {
    const int*   sentence = (const int*)d_in[0];
    const int*   speaker  = (const int*)d_in[1];
    const float* LutP = (const float*)d_in[2];
    const float* LutS = (const float*)d_in[3];
    const float* NaW  = (const float*)d_in[4];
    const float* NaB  = (const float*)d_in[5];
    const float* NuW  = (const float*)d_in[6];
    const float* NuB  = (const float*)d_in[7];
    const float* NoW  = (const float*)d_in[8];
    const float* NoB  = (const float*)d_in[9];
    const float* FuW  = (const float*)d_in[10];
    const float* FuB  = (const float*)d_in[11];
    const float* FoW  = (const float*)d_in[12];
    const float* FoB  = (const float*)d_in[13];
    const int*   Tptr = (const int*)d_in[14];
    float* ws   = (float*)d_ws;
    float* outp = (float*)d_out;

    hipLaunchKernelGGL(prep_kernel, dim3(2), dim3(1024), 0, stream, (int*)d_ws);
    hipLaunchKernelGGL(recur_kernel, dim3(BB * NPEER), dim3(NTH), 0, stream,
                       sentence, speaker, LutP, LutS, NaW, NaB,
                       NuW, NuB, NoW, NoB, FuW, FuB, FoW, FoB,
                       ws, Tptr, outp);
}

// Round 10
// 5342.947 us; speedup vs baseline: 3.5761x; 3.3118x over previous
//
#include <hip/hip_runtime.h>

#define DP   256
#define DD   320
#define KK   10
#define CC   10
#define DOUT 64
#define SEQn 512
#define BB   32
#define SI   100
#define NSL  32     // dim slices (10 dims each)
#define NGR  8      // batch groups
#define BPG  4      // batches per group
#define NTH  640
#define DPS  10
#define RPS  100    // flat S-rows per slice

// pubA entry (floats): uf[40] za[128] zo[256] pad -> 448
#define PSA   448
#define UF_O  0
#define ZA_O  40
#define ZO_O  168
#define HALF_A (NGR*NSL*PSA)
#define PSB   320   // pubB entry: col[320]

typedef float f4 __attribute__((ext_vector_type(4)));

__device__ __forceinline__ void llc_ld(f4* dst, const float* p) {
    f4 r;
    asm volatile("global_load_dwordx4 %0, %1, off sc0 sc1" : "=&v"(r) : "v"(p));
    asm volatile("s_waitcnt vmcnt(0)" ::: "memory");
    __builtin_amdgcn_sched_barrier(0);
    *dst = r;
}
__device__ __forceinline__ void llc_st(float* p, f4 v) {
    asm volatile("global_store_dwordx4 %0, %1, off sc0 sc1" :: "v"(p), "v"(v) : "memory");
}

__global__ void prep_kernel(int* ctr) {
    if (threadIdx.x < 256) ctr[threadIdx.x] = 0;
}

// 32-peer barrier (per group): drain own LLC stores, release-add, relaxed poll.
__device__ __forceinline__ void gbar(int* c, int target) {
    asm volatile("s_waitcnt vmcnt(0)" ::: "memory");
    __syncthreads();
    if (threadIdx.x == 0) {
        __hip_atomic_fetch_add(c, 1, __ATOMIC_RELEASE, __HIP_MEMORY_SCOPE_AGENT);
        while (__hip_atomic_load(c, __ATOMIC_RELAXED, __HIP_MEMORY_SCOPE_AGENT) < target)
            __builtin_amdgcn_s_sleep(2);
    }
    __syncthreads();
}

__global__ __launch_bounds__(NTH) void recur_kernel(
    const int* __restrict__ sentence, const int* __restrict__ speaker,
    const float* __restrict__ LutP, const float* __restrict__ LutS,
    const float* __restrict__ NaW,  const float* __restrict__ NaB,
    const float* __restrict__ NuW,  const float* __restrict__ NuB,
    const float* __restrict__ NoW,  const float* __restrict__ NoB,
    const float* __restrict__ FuW,  const float* __restrict__ FuB,
    const float* __restrict__ FoW,  const float* __restrict__ FoB,
    float* __restrict__ ws, const int* __restrict__ Tptr,
    float* __restrict__ out)
{
    const int tid  = threadIdx.x;
    const int s    = blockIdx.x & (NSL - 1);
    const int g    = blockIdx.x >> 5;
    const bool owner = (s < BPG);           // slice j owns batch g*4+j
    const int dbase = s * DPS;
    const int rbase = s * RPS;
    int*  ctr  = (int*)ws + g * 32;
    float* pubA = ws + 256;
    float* pubB = ws + 256 + 2 * HALF_A;

    const int c_   = tid >> 6;   // wave id = owned u-column 0..9
    const int lane = tid & 63;

    __shared__ float xsE[BPG][3328];     // state: 64 rgrp x 52 (50 used)
    __shared__ float wNa[RPS][32];
    __shared__ float wNo[RPS][65];
    __shared__ float naT0[DPS][32];
    __shared__ float noT0[DPS][65];
    __shared__ float identsh[BPG][DP];
    __shared__ float ufull[BPG][DD];
    __shared__ float colL[BPG][DD];
    __shared__ float ucol[BPG*DPS];      // final u for own dims (flat 40)
    __shared__ float zr[BPG*32];
    __shared__ float zor[BPG*DOUT];
    __shared__ float zastage[NSL][32];
    __shared__ float zostage[NSL][DOUT];
    __shared__ float fos[BPG][RPS];
    __shared__ float nubO[DPS];
    __shared__ float nabL[32];
    __shared__ float aoutL[32];
    __shared__ float muL[CC], sgL[CC], ggL[CC];
    __shared__ float alphaL[SEQn];
    __shared__ float histL[SI];
    __shared__ float idtF[DP];
    __shared__ float colF[DD];
    __shared__ float o_own[DOUT];
    __shared__ float foNoL[DOUT];
    __shared__ int   sentL[SEQn];
    __shared__ int   posidx[SEQn];
    __shared__ int   vstart[SI + 1];
    __shared__ int   vcnt[SI];

    // ---------------- prologue: stage weights ----------------
    for (int i = tid; i < RPS * 30; i += NTH) {
        int r = i / 30, c = i % 30;
        wNa[r][c] = NaW[(rbase + r) * 30 + c];
    }
    for (int i = tid; i < RPS * 64; i += NTH) {
        int r = i / 64, o = i % 64;
        wNo[r][o] = NoW[(rbase + r) * 64 + o];
    }
    if (tid < DPS * 30) { int dl = tid / 30, c = tid % 30; naT0[dl][c] = NaW[((dbase + dl) * KK) * 30 + c]; }
    if (tid < DPS * 64) { int dl = tid >> 6, o = tid & 63; noT0[dl][o] = NoW[((dbase + dl) * KK) * 64 + o]; }  // FIXED range
    if (tid < DPS) nubO[tid] = NuB[dbase + tid];
    if (tid >= 16 && tid < 48) { int c = tid - 16; nabL[c] = (c < 30) ? NaB[c] : 0.f; }
    for (int i = tid; i < BPG * DP; i += NTH) {
        int j = i / DP, v = i % DP;
        identsh[j][v] = LutS[speaker[g * BPG + j] * DP + v];
    }
    __syncthreads();

    // Nu column weights into registers: thread (c_, lane) holds rows lane*50..+49, col dbase+c_
    float w[50];
    #pragma unroll
    for (int q = 0; q < 50; ++q)
        w[q] = NuW[(size_t)(lane * 50 + q) * DD + dbase + c_];

    // fo rows for this slice (per batch)
    for (int i = tid; i < BPG * RPS; i += NTH) {
        int j = i / RPS, r = i % RPS;
        float acc = FoB[rbase + r];
        for (int v = 0; v < DP; v += 8) {
            float wv[8];
            #pragma unroll
            for (int e = 0; e < 8; ++e) wv[e] = FoW[(v + e) * 3200 + rbase + r];
            #pragma unroll
            for (int e = 0; e < 8; ++e) acc += identsh[j][v + e] * wv[e];
        }
        fos[j][r] = acc;
    }
    if (owner) {
        if (tid < DP) {
            float acc = FuB[tid];
            for (int v = 0; v < DP; v += 8) {
                float wv[8];
                #pragma unroll
                for (int e = 0; e < 8; ++e) wv[e] = FuW[(v + e) * DP + tid];
                #pragma unroll
                for (int e = 0; e < 8; ++e) acc += identsh[s][v + e] * wv[e];
            }
            idtF[tid] = tanhf(acc);
        }
        if (tid >= 512 && tid < 512 + CC) muL[tid - 512] = 0.f;
        if (tid < SEQn) sentL[tid] = sentence[(g * BPG + s) * SEQn + tid];
        __syncthreads();
        // bucket positions by vocab (deterministic ascending order)
        if (tid < SI) { int cnt = 0; for (int q = 0; q < SEQn; ++q) if (sentL[q] == tid) ++cnt; vcnt[tid] = cnt; }
        __syncthreads();
        if (tid == 0) { int run = 0; for (int v = 0; v < SI; ++v) { vstart[v] = run; run += vcnt[v]; } vstart[SI] = run; }
        __syncthreads();
        if (tid < SI) { int k = vstart[tid]; for (int q = 0; q < SEQn; ++q) if (sentL[q] == tid) posidx[k++] = q; }
    }
    // S0: every tap = [ident ; 0]
    for (int i = tid; i < BPG * 3200; i += NTH) {
        int j = i / 3200, row = i % 3200;
        int d = row / KK;
        xsE[j][(row / 50) * 52 + (row % 50)] = (d < DP) ? identsh[j][d] : 0.f;
    }
    __syncthreads();
    // za0 (all 100 rows, tap0 = real ident) and foNo parts
    if (tid < 128) {
        int j = tid >> 5, c = tid & 31;
        float acc = 0.f;
        if (c < 30)
            for (int rr = 0; rr < RPS; ++rr) {
                int row = rbase + rr;
                acc += xsE[j][(row / 50) * 52 + (row % 50)] * wNa[rr][c];
            }
        zr[j * 32 + c] = acc;
    }
    if (tid >= 128 && tid < 384) {
        int t = tid - 128, j = t >> 6, o = t & 63;
        float acc = 0.f;
        for (int rr = 0; rr < RPS; ++rr) acc += fos[j][rr] * wNo[rr][o];
        zor[j * 64 + o] = acc;
    }
    __syncthreads();
    {
        float* pa0 = pubA + (g * NSL + s) * PSA;   // half 0
        if (tid < 32) llc_st(pa0 + ZA_O + tid * 4, *(f4*)&zr[tid * 4]);
        if (tid >= 32 && tid < 96) { int q = tid - 32; llc_st(pa0 + ZO_O + q * 4, *(f4*)&zor[q * 4]); }
    }
    gbar(ctr, 32 * 1);

    const int T = Tptr[0];

    for (int i = 0; i < T; ++i) {
        const int rh = i & 1, wh = rh ^ 1;
        float* pa_r = pubA + rh * HALF_A + g * NSL * PSA;
        float* pa_w = pubA + wh * HALF_A + (g * NSL + s) * PSA;

        // ---- P1: read u_{i-1} finals (all slices) ----
        if (i > 0 && tid < 320) {
            int p = tid / 10, q = tid % 10;
            f4 v; llc_ld(&v, pa_r + p * PSA + UF_O + q * 4);
            #pragma unroll
            for (int e = 0; e < 4; ++e) {
                int f = q * 4 + e;           // j*10+dl
                ufull[f / 10][p * 10 + (f % 10)] = v[e];
            }
        }
        __syncthreads();

        // ---- owner: serial chain for its batch ----
        if (owner) {
            if (tid < 256) {
                int p = tid >> 3, q = tid & 7;
                f4 v; llc_ld(&v, pa_r + p * PSA + ZA_O + s * 32 + q * 4);
                #pragma unroll
                for (int e = 0; e < 4; ++e) zastage[p][q * 4 + e] = v[e];
            }
            if (tid < 512) {
                int p = tid >> 4, q = tid & 15;
                f4 v; llc_ld(&v, pa_r + p * PSA + ZO_O + s * 64 + q * 4);
                #pragma unroll
                for (int e = 0; e < 4; ++e) zostage[p][q * 4 + e] = v[e];
            }
            __syncthreads();
            if (tid < 30) {
                float a = nabL[tid];
                for (int p = 0; p < NSL; ++p) a += zastage[p][tid];
                aoutL[tid] = a;
            }
            if (tid >= 64 && tid < 128) {
                int o = tid - 64;
                float v = 0.f;
                for (int p = 0; p < NSL; ++p) v += zostage[p][o];
                if (i == 0) { foNoL[o] = NoB[o] + v; o_own[o] = 0.f; }
                else        o_own[o] = foNoL[o] + v;
            }
            __syncthreads();
            if (tid < CC) {
                muL[tid] += 0.05f * expf(aoutL[tid]);
                sgL[tid] = expf(aoutL[10 + tid]);
                float m = -1e30f;
                for (int q = 0; q < CC; ++q) m = fmaxf(m, aoutL[20 + q]);
                float ssum = 0.f;
                for (int q = 0; q < CC; ++q) ssum += expf(aoutL[20 + q] - m);
                ggL[tid] = expf(aoutL[20 + tid] - m) / ssum;
            }
            __syncthreads();
            if (tid < SEQn) {
                float J = (float)(tid + 1);
                float a = 0.f;
                #pragma unroll
                for (int c = 0; c < CC; ++c) { float dm = muL[c] - J; a += ggL[c] * __expf(-0.5f * sgL[c] * dm * dm); }
                alphaL[tid] = a * 0.3989422917366028f;
            }
            __syncthreads();
            if (tid < SI) {
                float h = 0.f;
                for (int k = vstart[tid]; k < vstart[tid + 1]; ++k) h += alphaL[posidx[k]];
                histL[tid] = h;
            }
            __syncthreads();
            if (tid < DP) {
                float acc = idtF[tid];
                for (int v = 0; v < SI; v += 10) {
                    float wv[10];
                    #pragma unroll
                    for (int e = 0; e < 10; ++e) wv[e] = LutP[(v + e) * DP + tid];
                    #pragma unroll
                    for (int e = 0; e < 10; ++e) acc += histL[v + e] * wv[e];
                }
                colF[tid] = acc;
            } else if (tid < DD) {
                colF[tid] = o_own[tid - DP] * (1.0f / 30.0f);
            }
            __syncthreads();
            if (i > 0 && tid < DOUT)
                out[((size_t)(i - 1) * BB + (g * BPG + s)) * DOUT + tid] = o_own[tid];
            if (tid < 80) llc_st(pubB + (g * BPG + s) * PSB + tid * 4, *(f4*)&colF[tid * 4]);
        }

        // ---- shift (all blocks): tap1 <- u_{i-1}; taps 2..9 <- old 1..8 ----
        for (int it = tid; it < BPG * DD; it += NTH) {
            int j = it / DD, d = it % DD;
            float* p = &xsE[j][(d / 5) * 52 + (d % 5) * 10];
            float t0 = p[0];
            float v1 = p[1], v2 = p[2], v3 = p[3], v4 = p[4], v5 = p[5], v6 = p[6], v7 = p[7], v8 = p[8];
            p[1] = (i == 0) ? t0 : ufull[j][d];
            p[2] = v1; p[3] = v2; p[4] = v3; p[5] = v4; p[6] = v5; p[7] = v6; p[8] = v7; p[9] = v8;
        }
        gbar(ctr, 32 * (2 * i + 2));   // barB: col published, shifts done

        // ---- P3: read C-columns, insert tap0 ----
        if (tid < 320) {
            int j = tid / 80, q = tid % 80;
            f4 v; llc_ld(&v, pubB + (g * BPG + j) * PSB + q * 4);
            #pragma unroll
            for (int e = 0; e < 4; ++e) colL[j][q * 4 + e] = v[e];
        }
        __syncthreads();
        for (int it = tid; it < BPG * DD; it += NTH) {
            int j = it / DD, d = it % DD;
            xsE[j][(d / 5) * 52 + (d % 5) * 10] = colL[j][d];
        }
        __syncthreads();

        // ---- E: final u for own 10 dims (weights in regs) ----
        {
            float accE[BPG];
            #pragma unroll
            for (int j = 0; j < BPG; ++j) {
                const float* xb = &xsE[j][lane * 52];
                float a = 0.f;
                #pragma unroll
                for (int qq = 0; qq < 12; ++qq) {
                    f4 x = *(const f4*)(xb + qq * 4);
                    a += x.x * w[qq * 4] + x.y * w[qq * 4 + 1] + x.z * w[qq * 4 + 2] + x.w * w[qq * 4 + 3];
                }
                a += xb[48] * w[48] + xb[49] * w[49];
                accE[j] = a;
            }
            #pragma unroll
            for (int j = 0; j < BPG; ++j)
                for (int off = 32; off; off >>= 1) accE[j] += __shfl_xor(accE[j], off, 64);
            if (lane == 0) {
                #pragma unroll
                for (int j = 0; j < BPG; ++j) ucol[j * DPS + c_] = accE[j] + nubO[c_];
            }
        }
        __syncthreads();

        // ---- za/zo partials for next step: k>=1 rows + own-final-u tap0 fold ----
        if (tid < 128) {
            int j = tid >> 5, c = tid & 31;
            float acc = 0.f;
            if (c < 30) {
                for (int dd = 0; dd < DPS; ++dd) {
                    int rg = 2 * s + (dd >= 5);
                    int of = dd * 10 - (dd >= 5 ? 50 : 0);
                    const float* xb = &xsE[j][rg * 52 + of];
                    #pragma unroll
                    for (int k = 1; k < KK; ++k) acc += xb[k] * wNa[dd * 10 + k][c];
                }
                #pragma unroll
                for (int dl = 0; dl < DPS; ++dl) acc += ucol[j * DPS + dl] * naT0[dl][c];
            }
            zr[j * 32 + c] = acc;
        }
        if (tid >= 128 && tid < 384) {
            int t = tid - 128, j = t >> 6, o = t & 63;
            float acc = 0.f;
            for (int dd = 0; dd < DPS; ++dd) {
                int rg = 2 * s + (dd >= 5);
                int of = dd * 10 - (dd >= 5 ? 50 : 0);
                const float* xb = &xsE[j][rg * 52 + of];
                #pragma unroll
                for (int k = 1; k < KK; ++k) acc += xb[k] * wNo[dd * 10 + k][o];
            }
            #pragma unroll
            for (int dl = 0; dl < DPS; ++dl) acc += ucol[j * DPS + dl] * noT0[dl][o];
            zor[j * 64 + o] = acc;
        }
        __syncthreads();

        // ---- publish uf / za / zo ----
        if (tid < 10)                llc_st(pa_w + UF_O + tid * 4,        *(f4*)&ucol[tid * 4]);
        if (tid >= 10 && tid < 42)  { int q = tid - 10; llc_st(pa_w + ZA_O + q * 4, *(f4*)&zr[q * 4]); }
        if (tid >= 42 && tid < 106) { int q = tid - 42; llc_st(pa_w + ZO_O + q * 4, *(f4*)&zor[q * 4]); }
        gbar(ctr, 32 * (2 * i + 3));   // barA
    }

    // ---- final output o_{T-1} (owner) ----
    if (owner) {
        float* pa_r = pubA + (T & 1) * HALF_A + g * NSL * PSA;
        if (tid < 512) {
            int p = tid >> 4, q = tid & 15;
            f4 v; llc_ld(&v, pa_r + p * PSA + ZO_O + s * 64 + q * 4);
            #pragma unroll
            for (int e = 0; e < 4; ++e) zostage[p][q * 4 + e] = v[e];
        }
        __syncthreads();
        if (tid < DOUT) {
            float v = foNoL[tid];
            for (int p = 0; p < NSL; ++p) v += zostage[p][tid];
            out[((size_t)(T - 1) * BB + (g * BPG + s)) * DOUT + tid] = v;
        }
    }
}

extern "C" void kernel_launch(void* const* d_in, const int* in_sizes, int n_in,
                              void* d_out, int out_size, void* d_ws, size_t ws_size,
                              hipStream_t stream) {
    const int*   sentence = (const int*)d_in[0];
    const int*   speaker  = (const int*)d_in[1];
    const float* LutP = (const float*)d_in[2];
    const float* LutS = (const float*)d_in[3];
    const float* NaW  = (const float*)d_in[4];
    const float* NaB  = (const float*)d_in[5];
    const float* NuW  = (const float*)d_in[6];
    const float* NuB  = (const float*)d_in[7];
    const float* NoW  = (const float*)d_in[8];
    const float* NoB  = (const float*)d_in[9];
    const float* FuW  = (const float*)d_in[10];
    const float* FuB  = (const float*)d_in[11];
    const float* FoW  = (const float*)d_in[12];
    const float* FoB  = (const float*)d_in[13];
    const int*   Tptr = (const int*)d_in[14];
    float* ws   = (float*)d_ws;
    float* outp = (float*)d_out;

    hipLaunchKernelGGL(prep_kernel, dim3(1), dim3(256), 0, stream, (int*)d_ws);
    hipLaunchKernelGGL(recur_kernel, dim3(NSL * NGR), dim3(NTH), 0, stream,
                       sentence, speaker, LutP, LutS, NaW, NaB,
                       NuW, NuB, NoW, NoB, FuW, FuB, FoW, FoB,
                       ws, Tptr, outp);
}